// Round 10
// baseline (2363.477 us; speedup 1.0000x reference)
//
#include <hip/hip_runtime.h>
#include <hip/hip_bf16.h>

// B=1024, T=64, D=256, H=256, C=96, num_steps = batch_max_length+1 = 26.
constexpr int B  = 1024;
constexpr int T  = 64;
constexpr int D  = 256;
constexpr int H  = 256;
constexpr int C  = 96;
constexpr int NS = 26;
constexpr int G  = 4 * H;    // 1024 gate columns (i,f,g,o)

typedef __attribute__((ext_vector_type(8))) short short8v;   // 8 bf16 (4 VGPR)
typedef __attribute__((ext_vector_type(4))) float f32x4;     // MFMA C/D

#define MFMA16 __builtin_amdgcn_mfma_f32_16x16x32_bf16

__device__ __forceinline__ float fsig(float x) {
    return __builtin_amdgcn_rcpf(1.0f + __expf(-x));
}
__device__ __forceinline__ float ftanh(float x) {
    float e = __expf(2.0f * x);
    return fmaf(-2.0f, __builtin_amdgcn_rcpf(e + 1.0f), 1.0f);
}
__device__ __forceinline__ float bf_lo(unsigned int p) {
    union { unsigned int i; float f; } v; v.i = p << 16; return v.f;
}
__device__ __forceinline__ float bf_hi(unsigned int p) {
    union { unsigned int i; float f; } v; v.i = p & 0xFFFF0000u; return v.f;
}
__device__ __forceinline__ unsigned short f2bf(float f) {
    __hip_bfloat16 h = __float2bfloat16(f);  // RNE
    return *reinterpret_cast<unsigned short*>(&h);
}

// ---------------------------------------------------------------------------
// batch_H (fp32) -> bf16, one-time.
__global__ __launch_bounds__(256) void cvt_kernel(
        const float* __restrict__ in, ushort* __restrict__ out) {
    const int i = blockIdx.x * 256 + threadIdx.x;
    const float4 v = reinterpret_cast<const float4*>(in)[i];
    ushort4 o;
    o.x = f2bf(v.x); o.y = f2bf(v.y); o.z = f2bf(v.z); o.w = f2bf(v.w);
    reinterpret_cast<ushort4*>(out)[i] = o;
}

// ---------------------------------------------------------------------------
// Pack W (fp32 [256 x ncols], row stride = wstride) into MFMA B-fragment order:
//   WF[((ct*8 + s)*64 + l)*8 + j] = bf16( W[s*32 + (l>>4)*8 + j][ct*16 + (l&15)] )
// A-side uses the SAME k-slot mapping, so the MFMA k-sum is correct under any
// internal k ordering (permutation-invariance of the dot product).
__global__ __launch_bounds__(256) void pack_frag_kernel(
        const float* __restrict__ W, ushort* __restrict__ WF,
        int ncol_tiles, int wstride) {
    const int i = blockIdx.x * 256 + threadIdx.x;   // (ct*8 + s)*64 + l
    const int l = i & 63;
    const int s = (i >> 6) & 7;
    const int ct = i >> 9;
    if (ct >= ncol_tiles) return;
    const int col = ct * 16 + (l & 15);
    const int k0 = s * 32 + (l >> 4) * 8;
    ushort o[8];
#pragma unroll
    for (int j = 0; j < 8; ++j) o[j] = f2bf(W[(size_t)(k0 + j) * wstride + col]);
    *reinterpret_cast<uint4*>(&WF[(size_t)i * 8]) = *reinterpret_cast<uint4*>(o);
}

// ---------------------------------------------------------------------------
// proj = batch_H @ Wi2h, stored BF16 in t-interleaved layout:
//   proj[b*H*T + (h/8)*T*8 + t*8 + (h%8)]   (unchanged from r9 - works)
__global__ __launch_bounds__(256) void proj_kernel(
        const float* __restrict__ bH, const float* __restrict__ Wi2h,
        ushort* __restrict__ proj) {
    __shared__ float xs[32 * 256];
    const int row0 = blockIdx.x * 32;
    const int tid = threadIdx.x;

    const float4* src = reinterpret_cast<const float4*>(bH + (size_t)row0 * D);
    float4* dst = reinterpret_cast<float4*>(xs);
#pragma unroll
    for (int i = 0; i < 8; ++i) dst[tid + 256 * i] = src[tid + 256 * i];
    __syncthreads();

    const int wv = tid >> 6, lane = tid & 63;
    const int r0 = wv * 8;
    const int c0 = lane * 4;
    float4 acc[8];
#pragma unroll
    for (int r = 0; r < 8; ++r) acc[r] = make_float4(0.f, 0.f, 0.f, 0.f);

    for (int k = 0; k < D; k += 4) {
        const float4 w0 = *reinterpret_cast<const float4*>(&Wi2h[(k + 0) * H + c0]);
        const float4 w1 = *reinterpret_cast<const float4*>(&Wi2h[(k + 1) * H + c0]);
        const float4 w2 = *reinterpret_cast<const float4*>(&Wi2h[(k + 2) * H + c0]);
        const float4 w3 = *reinterpret_cast<const float4*>(&Wi2h[(k + 3) * H + c0]);
#pragma unroll
        for (int r = 0; r < 8; ++r) {
            const float4 x = *reinterpret_cast<const float4*>(&xs[(r0 + r) * 256 + k]);
            acc[r].x = fmaf(x.x, w0.x, fmaf(x.y, w1.x, fmaf(x.z, w2.x, fmaf(x.w, w3.x, acc[r].x))));
            acc[r].y = fmaf(x.x, w0.y, fmaf(x.y, w1.y, fmaf(x.z, w2.y, fmaf(x.w, w3.y, acc[r].y))));
            acc[r].z = fmaf(x.x, w0.z, fmaf(x.y, w1.z, fmaf(x.z, w2.z, fmaf(x.w, w3.z, acc[r].z))));
            acc[r].w = fmaf(x.x, w0.w, fmaf(x.y, w1.w, fmaf(x.z, w2.w, fmaf(x.w, w3.w, acc[r].w))));
        }
    }
#pragma unroll
    for (int r = 0; r < 8; ++r) {
        const int brow = row0 + r0 + r;
        const int bb = brow >> 6, tt = brow & 63;
        ushort4 o;
        o.x = f2bf(acc[r].x); o.y = f2bf(acc[r].y);
        o.z = f2bf(acc[r].z); o.w = f2bf(acc[r].w);
        *reinterpret_cast<ushort4*>(
            &proj[(size_t)bb * H * T + (c0 >> 3) * (T * 8) + tt * 8 + (c0 & 7)]) = o;
    }
}

// ---------------------------------------------------------------------------
// A-fragment read from a 16x256-bf16 LDS tile, XOR-swizzled (G4).
// element (row, k) lives at byte (row*512 + k*2) ^ ((row&7)<<4).
__device__ __forceinline__ short8v ldA(const ushort* base, int lane, int s) {
    const int row = lane & 15, g = lane >> 4;
    const int byte = ((row << 9) + (s << 6) + (g << 4)) ^ ((row & 7) << 4);
    return *reinterpret_cast<const short8v*>(
        reinterpret_cast<const char*>(base) + byte);
}
__device__ __forceinline__ void loadB(short8v dst[8], const ushort* __restrict__ wf,
                                      int ctg, int lane) {
#pragma unroll
    for (int s = 0; s < 8; ++s)
        dst[s] = *reinterpret_cast<const short8v*>(
            wf + (((size_t)ctg * 8 + s) * 64 + lane) * 8);
}
__device__ __forceinline__ f32x4 mfma_hilo(const short8v aHi[8], const short8v aLo[8],
                                           const short8v b[8]) {
    f32x4 acc = {0.f, 0.f, 0.f, 0.f};
#pragma unroll
    for (int s = 0; s < 8; ++s) {
        acc = MFMA16(aLo[s], b[s], acc, 0, 0, 0);
        acc = MFMA16(aHi[s], b[s], acc, 0, 0, 0);
    }
    return acc;
}

// ---------------------------------------------------------------------------
// Persistent decoder: 256 blocks x 512 thr (8 waves), 4 rows/block, 26 steps.
//   S1: waves 0-3 attention (row=wave) ; waves 4-7: gates = h@Wh via MFMA
//   S2: all 8 waves: gates += ctx@Wx via MFMA
//   S3: pointwise (adds bias+onehot) -> c, h (fp32->hi/lo bf16), hiddens
//   S4: hp = h@Wh2h + bh2h via MFMA
// h/ctx are hi+lo bf16 pairs -> GEMM inputs are fp32-accurate; MFMA M=16 with
// rows 4-15 zeroed (they only pollute ignored C rows).
__global__ __launch_bounds__(512, 2) void decoder_kernel(
        const ushort* __restrict__ proj, const ushort* __restrict__ bHb,
        const int* __restrict__ text, const float* __restrict__ Wx,
        const ushort* __restrict__ WhF, const ushort* __restrict__ WxF,
        const ushort* __restrict__ Wh2hF, const float* __restrict__ b_lstm,
        const float* __restrict__ bh2h, const float* __restrict__ w_score,
        float* __restrict__ hiddens) {
    __shared__ float hp_s[4][256];
    __shared__ float c_s[4][256];
    __shared__ float gates[4][1024];
    __shared__ float alpha_s[4][64];
    __shared__ float ws_s[256];
    __shared__ ushort hHi[16 * 256], hLo[16 * 256];
    __shared__ ushort cHi[16 * 256], cLo[16 * 256];

    const int row0 = blockIdx.x * 4;
    const int tid = threadIdx.x;
    const int wv = tid >> 6, lane = tid & 63;

    for (int i = tid; i < 4096; i += 512) {
        hHi[i] = 0; hLo[i] = 0; cHi[i] = 0; cLo[i] = 0;
    }
    for (int i = tid; i < 1024; i += 512) {
        const int r = i >> 8, j = i & 255;
        c_s[r][j] = 0.0f;
        hp_s[r][j] = bh2h[j];
    }
    if (tid < 256) ws_s[tid] = w_score[tid];
    __syncthreads();

    for (int t = 0; t < NS; ++t) {
        // ================= S1 =================
        if (wv < 4) {
            const int r = wv;
            // scores: lane = timestep, coalesced t-interleaved proj stream
            const ushort* pb = proj + (size_t)(row0 + r) * H * T + lane * 8;
            float e = 0.0f;
#pragma unroll 8
            for (int h = 0; h < H; h += 8) {
                const uint4 pv = *reinterpret_cast<const uint4*>(pb + (h >> 3) * (T * 8));
                const float4 hp0 = *reinterpret_cast<const float4*>(&hp_s[r][h]);
                const float4 hp1 = *reinterpret_cast<const float4*>(&hp_s[r][h + 4]);
                const float4 w0 = *reinterpret_cast<const float4*>(&ws_s[h]);
                const float4 w1 = *reinterpret_cast<const float4*>(&ws_s[h + 4]);
                e += ftanh(bf_lo(pv.x) + hp0.x) * w0.x;
                e += ftanh(bf_hi(pv.x) + hp0.y) * w0.y;
                e += ftanh(bf_lo(pv.y) + hp0.z) * w0.z;
                e += ftanh(bf_hi(pv.y) + hp0.w) * w0.w;
                e += ftanh(bf_lo(pv.z) + hp1.x) * w1.x;
                e += ftanh(bf_hi(pv.z) + hp1.y) * w1.y;
                e += ftanh(bf_lo(pv.w) + hp1.z) * w1.z;
                e += ftanh(bf_hi(pv.w) + hp1.w) * w1.w;
            }
            // softmax across 64 lanes (= 64 timesteps)
            {
                float m = e;
#pragma unroll
                for (int off = 32; off > 0; off >>= 1) m = fmaxf(m, __shfl_xor(m, off));
                const float p = __expf(e - m);
                float sum = p;
#pragma unroll
                for (int off = 32; off > 0; off >>= 1) sum += __shfl_xor(sum, off);
                alpha_s[r][lane] = p * __builtin_amdgcn_rcpf(sum);
            }
            // context: lane = d-slot; write hi/lo bf16 swizzled for MFMA A
            {
                const ushort* xb = bHb + (size_t)(row0 + r) * T * D + lane * 4;
                float4 cacc = make_float4(0.f, 0.f, 0.f, 0.f);
#pragma unroll 8
                for (int tt = 0; tt < T; ++tt) {
                    const ushort4 x4 = *reinterpret_cast<const ushort4*>(xb + tt * D);
                    const float av = alpha_s[r][tt];
                    cacc.x = fmaf(av, bf_lo((unsigned)x4.x), cacc.x);
                    cacc.y = fmaf(av, bf_lo((unsigned)x4.y), cacc.y);
                    cacc.z = fmaf(av, bf_lo((unsigned)x4.z), cacc.z);
                    cacc.w = fmaf(av, bf_lo((unsigned)x4.w), cacc.w);
                }
                ushort4 hi, lo;
                hi.x = f2bf(cacc.x); lo.x = f2bf(cacc.x - bf_lo((unsigned)hi.x));
                hi.y = f2bf(cacc.y); lo.y = f2bf(cacc.y - bf_lo((unsigned)hi.y));
                hi.z = f2bf(cacc.z); lo.z = f2bf(cacc.z - bf_lo((unsigned)hi.z));
                hi.w = f2bf(cacc.w); lo.w = f2bf(cacc.w - bf_lo((unsigned)hi.w));
                const int byte = ((r << 9) + (lane << 3)) ^ ((r & 7) << 4);
                *reinterpret_cast<ushort4*>(reinterpret_cast<char*>(cHi) + byte) = hi;
                *reinterpret_cast<ushort4*>(reinterpret_cast<char*>(cLo) + byte) = lo;
            }
        } else {
            // gates = h @ Wh via MFMA (wave owns 16 col-tiles = 256 cols)
            short8v aHi[8], aLo[8];
#pragma unroll
            for (int s = 0; s < 8; ++s) { aHi[s] = ldA(hHi, lane, s); aLo[s] = ldA(hLo, lane, s); }
            const int ct0 = (wv - 4) * 16;
            short8v bA[8], bB[8];
            loadB(bA, WhF, ct0, lane);
#pragma unroll
            for (int ct = 0; ct < 16; ct += 2) {
                loadB(bB, WhF, ct0 + ct + 1, lane);
                f32x4 acc = mfma_hilo(aHi, aLo, bA);
                if (lane < 16) {
                    const int col = (ct0 + ct) * 16 + lane;
                    gates[0][col] = acc[0]; gates[1][col] = acc[1];
                    gates[2][col] = acc[2]; gates[3][col] = acc[3];
                }
                if (ct + 2 < 16) loadB(bA, WhF, ct0 + ct + 2, lane);
                acc = mfma_hilo(aHi, aLo, bB);
                if (lane < 16) {
                    const int col = (ct0 + ct + 1) * 16 + lane;
                    gates[0][col] = acc[0]; gates[1][col] = acc[1];
                    gates[2][col] = acc[2]; gates[3][col] = acc[3];
                }
            }
        }
        __syncthreads();

        // ================= S2: gates += ctx @ Wx (all 8 waves, MFMA) ========
        {
            short8v aHi[8], aLo[8];
#pragma unroll
            for (int s = 0; s < 8; ++s) { aHi[s] = ldA(cHi, lane, s); aLo[s] = ldA(cLo, lane, s); }
            const int ct0 = wv * 8;
            short8v bA[8], bB[8];
            loadB(bA, WxF, ct0, lane);
#pragma unroll
            for (int ct = 0; ct < 8; ct += 2) {
                loadB(bB, WxF, ct0 + ct + 1, lane);
                f32x4 acc = mfma_hilo(aHi, aLo, bA);
                if (lane < 16) {
                    const int col = (ct0 + ct) * 16 + lane;
                    gates[0][col] += acc[0]; gates[1][col] += acc[1];
                    gates[2][col] += acc[2]; gates[3][col] += acc[3];
                }
                if (ct + 2 < 8) loadB(bA, WxF, ct0 + ct + 2, lane);
                acc = mfma_hilo(aHi, aLo, bB);
                if (lane < 16) {
                    const int col = (ct0 + ct + 1) * 16 + lane;
                    gates[0][col] += acc[0]; gates[1][col] += acc[1];
                    gates[2][col] += acc[2]; gates[3][col] += acc[3];
                }
            }
        }
        __syncthreads();

        // ================= S3: pointwise LSTM (bias + onehot here) ==========
#pragma unroll
        for (int pp = 0; pp < 2; ++pp) {
            const int r = (tid >> 8) + pp * 2;
            const int j = tid & 255;
            const int ch = text[(row0 + r) * NS + t];
            const float* oh = Wx + (size_t)(D + ch) * G;
            const float gi = gates[r][j]       + b_lstm[j]       + oh[j];
            const float gf = gates[r][256 + j] + b_lstm[256 + j] + oh[256 + j];
            const float gc = gates[r][512 + j] + b_lstm[512 + j] + oh[512 + j];
            const float go = gates[r][768 + j] + b_lstm[768 + j] + oh[768 + j];
            const float cv = fsig(gf) * c_s[r][j] + fsig(gi) * ftanh(gc);
            c_s[r][j] = cv;
            const float hvv = fsig(go) * ftanh(cv);
            hiddens[((size_t)(row0 + r) * NS + t) * H + j] = hvv;
            const ushort hi = f2bf(hvv);
            const ushort lo = f2bf(hvv - bf_lo((unsigned)hi));
            const int byte = ((r << 9) + (j << 1)) ^ ((r & 7) << 4);
            *reinterpret_cast<ushort*>(reinterpret_cast<char*>(hHi) + byte) = hi;
            *reinterpret_cast<ushort*>(reinterpret_cast<char*>(hLo) + byte) = lo;
        }
        __syncthreads();

        // ================= S4: hp = h @ Wh2h + bh2h (MFMA, 2 tiles/wave) ====
        {
            short8v aHi[8], aLo[8];
#pragma unroll
            for (int s = 0; s < 8; ++s) { aHi[s] = ldA(hHi, lane, s); aLo[s] = ldA(hLo, lane, s); }
            short8v b0[8], b1[8];
            loadB(b0, Wh2hF, wv * 2 + 0, lane);
            loadB(b1, Wh2hF, wv * 2 + 1, lane);
            f32x4 acc0 = mfma_hilo(aHi, aLo, b0);
            f32x4 acc1 = mfma_hilo(aHi, aLo, b1);
            if (lane < 16) {
                int col = (wv * 2 + 0) * 16 + lane;
                float bb = bh2h[col];
                hp_s[0][col] = acc0[0] + bb; hp_s[1][col] = acc0[1] + bb;
                hp_s[2][col] = acc0[2] + bb; hp_s[3][col] = acc0[3] + bb;
                col = (wv * 2 + 1) * 16 + lane;
                bb = bh2h[col];
                hp_s[0][col] = acc1[0] + bb; hp_s[1][col] = acc1[1] + bb;
                hp_s[2][col] = acc1[2] + bb; hp_s[3][col] = acc1[3] + bb;
            }
        }
        __syncthreads();
    }
}

// ---------------------------------------------------------------------------
// probs[bt][cls] = hiddens[bt][:] @ Wg + bg
__global__ __launch_bounds__(192) void gen_kernel(
        const float* __restrict__ hiddens, const float* __restrict__ Wg,
        const float* __restrict__ bg, float* __restrict__ out) {
    const int row0 = blockIdx.x * 16 + (threadIdx.x / 96) * 8;
    const int cc = threadIdx.x % 96;
    float acc[8];
    const float bias = bg[cc];
#pragma unroll
    for (int r = 0; r < 8; ++r) acc[r] = bias;
    for (int k = 0; k < H; k += 4) {
        const float w0 = Wg[(k + 0) * C + cc];
        const float w1 = Wg[(k + 1) * C + cc];
        const float w2 = Wg[(k + 2) * C + cc];
        const float w3 = Wg[(k + 3) * C + cc];
#pragma unroll
        for (int r = 0; r < 8; ++r) {
            const float4 x = *reinterpret_cast<const float4*>(
                &hiddens[(size_t)(row0 + r) * H + k]);
            acc[r] = fmaf(x.x, w0, acc[r]);
            acc[r] = fmaf(x.y, w1, acc[r]);
            acc[r] = fmaf(x.z, w2, acc[r]);
            acc[r] = fmaf(x.w, w3, acc[r]);
        }
    }
#pragma unroll
    for (int r = 0; r < 8; ++r) out[(size_t)(row0 + r) * C + cc] = acc[r];
}

// ---------------------------------------------------------------------------
extern "C" void kernel_launch(void* const* d_in, const int* in_sizes, int n_in,
                              void* d_out, int out_size, void* d_ws, size_t ws_size,
                              hipStream_t stream) {
    const float* batch_H = (const float*)d_in[0];
    const int*   text    = (const int*)d_in[1];
    // d_in[2] = batch_max_length (scalar) -> NS hardcoded (out_size/B/C = 26)
    const float* Wi2h    = (const float*)d_in[3];
    const float* Wh2h    = (const float*)d_in[4];
    const float* bh2h    = (const float*)d_in[5];
    const float* w_score = (const float*)d_in[6];
    const float* Wx      = (const float*)d_in[7];
    const float* Wh      = (const float*)d_in[8];
    const float* b_lstm  = (const float*)d_in[9];
    const float* Wg      = (const float*)d_in[10];
    const float* bg      = (const float*)d_in[11];
    float* out = (float*)d_out;

    // workspace: proj 33.5MB | bH_bf 33.5MB | hiddens 27.3MB | WhF .5 | WxF .5 | Wh2hF .125
    char* wsb = (char*)d_ws;
    ushort* proj_bf = (ushort*)wsb;                                   // B*T*H
    ushort* bH_bf   = (ushort*)(wsb + (size_t)B * T * H * 2);         // B*T*D
    float*  hiddens = (float*)(wsb + (size_t)B * T * H * 2 * 2);      // B*NS*H
    ushort* WhF     = (ushort*)(wsb + (size_t)B * T * H * 2 * 2 +
                                (size_t)B * NS * H * 4);              // 256*1024 bf16
    ushort* WxF     = WhF + (size_t)256 * 1024;                       // 256*1024 bf16
    ushort* Wh2hF   = WxF + (size_t)256 * 1024;                       // 256*256  bf16

    cvt_kernel<<<B * T * D / 4 / 256, 256, 0, stream>>>(batch_H, bH_bf);
    pack_frag_kernel<<<128, 256, 0, stream>>>(Wh, WhF, 64, G);
    pack_frag_kernel<<<128, 256, 0, stream>>>(Wx, WxF, 64, G);   // k-rows 0..255
    pack_frag_kernel<<<32, 256, 0, stream>>>(Wh2h, Wh2hF, 16, H);
    proj_kernel<<<B * T / 32, 256, 0, stream>>>(batch_H, Wi2h, proj_bf);
    decoder_kernel<<<B / 4, 512, 0, stream>>>(proj_bf, bH_bf, text, Wx, WhF, WxF,
                                              Wh2hF, b_lstm, bh2h, w_score, hiddens);
    gen_kernel<<<B * NS / 16, 192, 0, stream>>>(hiddens, Wg, bg, out);
}